// Round 7
// baseline (343.300 us; speedup 1.0000x reference)
//
#include <hip/hip_runtime.h>

typedef unsigned int u32;
typedef unsigned short u16;
typedef __attribute__((ext_vector_type(8))) short short8;
typedef __attribute__((ext_vector_type(4))) float f32x4;
typedef __attribute__((ext_vector_type(16))) float f32x16;

static __device__ __forceinline__ u16 f2bf(float f) {
    u32 u = __builtin_bit_cast(u32, f);
    u32 r = (u + 0x7fffu + ((u >> 16) & 1u)) >> 16;   // round-to-nearest-even
    return (u16)r;
}
static __device__ __forceinline__ float bf2f(u16 b) {
    return __builtin_bit_cast(float, ((u32)b) << 16);
}

// fast erf-based exact-GELU (Abramowitz-Stegun 7.1.26, |eps|<=1.5e-7)
static __device__ __forceinline__ float fast_gelu(float v) {
    float z = fabsf(v) * 0.70710678118654752f;
    float t = __builtin_amdgcn_rcpf(1.f + 0.3275911f * z);
    float poly = t * (0.254829592f + t * (-0.284496736f + t * (1.421413741f
               + t * (-1.453152027f + t * 1.061405429f))));
    float e = __expf(-z * z);
    float erfz = 1.f - poly * e;
    float sgn = v < 0.f ? -erfz : erfz;
    return 0.5f * v * (1.f + sgn);
}

static __device__ __forceinline__ void cvt_seg(const float* __restrict__ s, u16* __restrict__ d,
                                               int n4, int base, int stride) {
    for (int i = base; i < n4; i += stride) {
        float4 v = ((const float4*)s)[i];
        ushort4 p;
        p.x = f2bf(v.x); p.y = f2bf(v.y); p.z = f2bf(v.z); p.w = f2bf(v.w);
        ((ushort4*)d)[i] = p;
    }
}

static __device__ __forceinline__ void ln_row(const float* __restrict__ x, const float* __restrict__ w,
                                              const float* __restrict__ b, u16* __restrict__ out,
                                              int row, int t) {
    const float4* xr = (const float4*)(x + (size_t)row * 512);
    float4 v0 = xr[t * 2], v1 = xr[t * 2 + 1];
    float s  = v0.x + v0.y + v0.z + v0.w + v1.x + v1.y + v1.z + v1.w;
    float s2 = v0.x*v0.x + v0.y*v0.y + v0.z*v0.z + v0.w*v0.w
             + v1.x*v1.x + v1.y*v1.y + v1.z*v1.z + v1.w*v1.w;
    #pragma unroll
    for (int off = 32; off >= 1; off >>= 1) {
        s  += __shfl_xor(s, off);
        s2 += __shfl_xor(s2, off);
    }
    float mu   = s * (1.f / 512.f);
    float var  = s2 * (1.f / 512.f) - mu * mu;
    float rstd = rsqrtf(var + 1e-5f);
    int c = t * 8;
    float xv[8] = {v0.x, v0.y, v0.z, v0.w, v1.x, v1.y, v1.z, v1.w};
    short8 pk;
    #pragma unroll
    for (int j = 0; j < 8; ++j) {
        float y = (xv[j] - mu) * rstd * w[c + j] + b[c + j];
        pk[j] = (short)f2bf(y);
    }
    *(short8*)(out + (size_t)row * 512 + c) = pk;
}

// ---------------- LayerNorm (C=512), one row per 64-thread block ----------------
__global__ __launch_bounds__(64)
void ln_kernel(const float* __restrict__ x, const float* __restrict__ w,
               const float* __restrict__ b, u16* __restrict__ out) {
    ln_row(x, w, b, out, blockIdx.x, threadIdx.x);
}

// ---------------- fused: LN1 (blocks < 25088) + weight cvt (blocks >= 25088) ----------------
__global__ __launch_bounds__(64)
void ln_cvt_kernel(const float* __restrict__ x, const float* __restrict__ w,
                   const float* __restrict__ b, u16* __restrict__ out,
                   const float* s0, u16* d0, const float* s1, u16* d1,
                   const float* s2, u16* d2, const float* s3, u16* d3) {
    if (blockIdx.x < 25088) {
        ln_row(x, w, b, out, blockIdx.x, threadIdx.x);
    } else {
        int base = (blockIdx.x - 25088) * 64 + threadIdx.x;
        const int stride = 1024 * 64;
        cvt_seg(s0, d0, 131072, base, stride);   // qkv_w  524288/4
        cvt_seg(s1, d1, 65536,  base, stride);   // proj_w 262144/4
        cvt_seg(s2, d2, 262144, base, stride);   // fc1_w 1048576/4
        cvt_seg(s3, d3, 262144, base, stride);   // fc2_w 1048576/4
    }
}

// ---------------- bf16 MFMA GEMM: out[M,N] = A[M,K] @ W[N,K]^T + bias (+epilogue) ----------------
// 128x128 tile, BK=64, 4 waves (2x2 of 64x64), inner = mfma_f32_32x32x16_bf16
// (2x2 frags of 32x32 per wave, 4 k-slices of 16). Same LDS layout/swizzle as before.
#define EPI_BF16 0
#define EPI_RES  1
#define EPI_GELU 2

template<int EPI>
__global__ __launch_bounds__(256, 2)
void gemm_kernel(const u16* __restrict__ A, const u16* __restrict__ W,
                 const float* __restrict__ bias, const float* resid,
                 void* out, int N, int K) {
    __shared__ __attribute__((aligned(16))) char ldsA[128 * 64 * 2];
    __shared__ __attribute__((aligned(16))) char ldsB[128 * 64 * 2];
    const int tid  = threadIdx.x;
    const int lane = tid & 63;
    const int wid  = tid >> 6;

    // XCD-chunked block swizzle: each XCD gets a contiguous tile range (x-fast)
    u32 nbx = gridDim.x;
    u32 bid = blockIdx.y * nbx + blockIdx.x;
    u32 nb  = nbx * gridDim.y;
    u32 tile = bid;
    if ((nb & 7u) == 0u) tile = (bid & 7u) * (nb >> 3) + (bid >> 3);
    const int tileM = (int)(tile / nbx) * 128;
    const int tileN = (int)(tile % nbx) * 128;

    const int waveM = (wid >> 1) * 64;
    const int waveN = (wid & 1) * 64;
    const int r8 = lane >> 3, c8 = lane & 7;
    const int swz = (c8 ^ r8) * 8;          // inverse-swizzled source column (elements)
    const int l31 = lane & 31, q5 = lane >> 5;

    f32x16 acc[2][2] = {};

    const char* Ab = (const char*)A;
    const char* Wb = (const char*)W;

    for (int k0 = 0; k0 < K; k0 += 64) {
        #pragma unroll
        for (int i = 0; i < 4; ++i) {
            int chunk = wid * 4 + i;            // wave-uniform
            int row = chunk * 8 + r8;
            const char* ga = Ab + ((size_t)(tileM + row) * K + k0 + swz) * 2;
            const char* gb = Wb + ((size_t)(tileN + row) * K + k0 + swz) * 2;
            __builtin_amdgcn_global_load_lds((const __attribute__((address_space(1))) u32*)ga,
                (__attribute__((address_space(3))) u32*)(ldsA + chunk * 1024), 16, 0, 0);
            __builtin_amdgcn_global_load_lds((const __attribute__((address_space(1))) u32*)gb,
                (__attribute__((address_space(3))) u32*)(ldsB + chunk * 1024), 16, 0, 0);
        }
        __syncthreads();
        #pragma unroll
        for (int ks = 0; ks < 4; ++ks) {
            // k-slice of 16: lane holds k = ks*16 + q5*8 + e (identical map for A and B)
            short8 aF[2], bF[2];
            int kByte = ks * 32 + q5 * 16;
            #pragma unroll
            for (int m = 0; m < 2; ++m) {
                int row = waveM + m * 32 + l31;
                aF[m] = *(const short8*)(ldsA + row * 128 + (kByte ^ ((row & 7) << 4)));
            }
            #pragma unroll
            for (int n = 0; n < 2; ++n) {
                int row = waveN + n * 32 + l31;
                bF[n] = *(const short8*)(ldsB + row * 128 + (kByte ^ ((row & 7) << 4)));
            }
            #pragma unroll
            for (int m = 0; m < 2; ++m)
                #pragma unroll
                for (int n = 0; n < 2; ++n)
                    acc[m][n] = __builtin_amdgcn_mfma_f32_32x32x16_bf16(aF[m], bF[n], acc[m][n], 0, 0, 0);
        }
        __syncthreads();
    }

    // epilogue: 32x32 C/D layout col = lane&31, row = (reg&3) + 8*(reg>>2) + 4*(lane>>5)
    #pragma unroll
    for (int m = 0; m < 2; ++m) {
        #pragma unroll
        for (int n = 0; n < 2; ++n) {
            int col = tileN + waveN + n * 32 + l31;
            float bv = bias[col];
            #pragma unroll
            for (int r = 0; r < 16; ++r) {
                int row = tileM + waveM + m * 32 + 4 * q5 + (r & 3) + 8 * (r >> 2);
                float v = acc[m][n][r] + bv;
                if (EPI == EPI_GELU) v = fast_gelu(v);
                if (EPI == EPI_RES) {
                    v += resid[(size_t)row * N + col];
                    ((float*)out)[(size_t)row * N + col] = v;
                } else {
                    ((u16*)out)[(size_t)row * N + col] = f2bf(v);
                }
            }
        }
    }
}

// ---------------- MFMA attention: 1 wave per (window, head), 49 padded to 64 ----------------
__global__ __launch_bounds__(64)
void attn_kernel(const u16* __restrict__ kv, const float* __restrict__ qg,
                 const float* __restrict__ bt, u16* __restrict__ ao) {
    __shared__ u16 Vt[32][72];   // V^T, 144B pitch -> bank stride 4, 2-way (free)
    __shared__ u16 P[64][72];    // P[i][j] bf16, same pitch
    const int lane = threadIdx.x;
    const int q4 = lane >> 4, r15 = lane & 15;
    const int head = blockIdx.x & 15;
    const int w = blockIdx.x >> 4;
    const int b = w >> 4, win = w & 15, wy = win >> 2, wx = win & 3;
    const int rowbase = (b * 28 + wy * 7) * 28 + wx * 7;

    short8 kF[4];
    #pragma unroll
    for (int mj = 0; mj < 4; ++mj) {
        int j = mj * 16 + r15; int jc = j < 49 ? j : 48;
        int tok = rowbase + (jc / 7) * 28 + (jc % 7);
        kF[mj] = *(const short8*)(kv + (size_t)tok * 1024 + head * 32 + q4 * 8);
    }
    short8 qF[4];
    const float* qbase = qg + ((size_t)(b * 16 + head)) * 49 * 32;
    #pragma unroll
    for (int ni = 0; ni < 4; ++ni) {
        int i = ni * 16 + r15; int ic = i < 49 ? i : 48;
        const float4* qr = (const float4*)(qbase + ic * 32 + q4 * 8);
        float4 a = qr[0], c = qr[1];
        short8 f;
        f[0] = (short)f2bf(a.x * 0.17677669529663687f);
        f[1] = (short)f2bf(a.y * 0.17677669529663687f);
        f[2] = (short)f2bf(a.z * 0.17677669529663687f);
        f[3] = (short)f2bf(a.w * 0.17677669529663687f);
        f[4] = (short)f2bf(c.x * 0.17677669529663687f);
        f[5] = (short)f2bf(c.y * 0.17677669529663687f);
        f[6] = (short)f2bf(c.z * 0.17677669529663687f);
        f[7] = (short)f2bf(c.w * 0.17677669529663687f);
        qF[ni] = f;
    }
    {
        int j = lane;
        short8 v0 = {}, v1 = {}, v2 = {}, v3 = {};
        if (j < 49) {
            int tok = rowbase + (j / 7) * 28 + (j % 7);
            const short8* vr = (const short8*)(kv + (size_t)tok * 1024 + 512 + head * 32);
            v0 = vr[0]; v1 = vr[1]; v2 = vr[2]; v3 = vr[3];
        }
        #pragma unroll
        for (int e = 0; e < 8; ++e) {
            Vt[e][j]      = (u16)v0[e];
            Vt[8 + e][j]  = (u16)v1[e];
            Vt[16 + e][j] = (u16)v2[e];
            Vt[24 + e][j] = (u16)v3[e];
        }
    }

    f32x4 s[4][4];
    __builtin_amdgcn_s_setprio(1);
    #pragma unroll
    for (int mj = 0; mj < 4; ++mj)
        #pragma unroll
        for (int ni = 0; ni < 4; ++ni)
            s[mj][ni] = __builtin_amdgcn_mfma_f32_16x16x32_bf16(kF[mj], qF[ni], (f32x4){0.f,0.f,0.f,0.f}, 0, 0, 0);
    __builtin_amdgcn_s_setprio(0);

    int tj16[4][4]; bool jok[4][4];
    #pragma unroll
    for (int mj = 0; mj < 4; ++mj)
        #pragma unroll
        for (int r = 0; r < 4; ++r) {
            int j = mj * 16 + q4 * 4 + r;
            int jc = j < 49 ? j : 48;
            tj16[mj][r] = ((jc / 7) * 13 + (jc % 7)) * 16;
            jok[mj][r] = (j < 49);
        }

    #pragma unroll
    for (int ni = 0; ni < 4; ++ni) {
        int i = ni * 16 + r15; int ic = i < 49 ? i : 48;
        const float* btbase = bt + (((ic / 7) * 13 + (ic % 7)) + 84) * 16 + head;
        float mx = -1e30f;
        #pragma unroll
        for (int mj = 0; mj < 4; ++mj)
            #pragma unroll
            for (int r = 0; r < 4; ++r) {
                float v = s[mj][ni][r] + btbase[-tj16[mj][r]];
                v = jok[mj][r] ? v : -1e30f;
                s[mj][ni][r] = v;
                mx = fmaxf(mx, v);
            }
        mx = fmaxf(mx, __shfl_xor(mx, 16));
        mx = fmaxf(mx, __shfl_xor(mx, 32));
        float l = 0.f;
        #pragma unroll
        for (int mj = 0; mj < 4; ++mj)
            #pragma unroll
            for (int r = 0; r < 4; ++r) {
                float p = __expf(s[mj][ni][r] - mx);
                s[mj][ni][r] = p;
                l += p;
            }
        l += __shfl_xor(l, 16);
        l += __shfl_xor(l, 32);
        float inv = 1.f / l;
        #pragma unroll
        for (int mj = 0; mj < 4; ++mj) {
            ushort4 pk;
            pk.x = f2bf(s[mj][ni][0] * inv);
            pk.y = f2bf(s[mj][ni][1] * inv);
            pk.z = f2bf(s[mj][ni][2] * inv);
            pk.w = f2bf(s[mj][ni][3] * inv);
            *(ushort4*)&P[i][mj * 16 + q4 * 4] = pk;
        }
    }
    __syncthreads();

    f32x4 o[4][2] = {};
    __builtin_amdgcn_s_setprio(1);
    #pragma unroll
    for (int ks = 0; ks < 2; ++ks) {
        short8 vB0 = *(const short8*)&Vt[r15][ks * 16 + q4 * 8];
        short8 vB1 = *(const short8*)&Vt[16 + r15][ks * 16 + q4 * 8];
        #pragma unroll
        for (int mi = 0; mi < 4; ++mi) {
            short8 pA = *(const short8*)&P[mi * 16 + r15][ks * 16 + q4 * 8];
            o[mi][0] = __builtin_amdgcn_mfma_f32_16x16x32_bf16(pA, vB0, o[mi][0], 0, 0, 0);
            o[mi][1] = __builtin_amdgcn_mfma_f32_16x16x32_bf16(pA, vB1, o[mi][1], 0, 0, 0);
        }
    }
    __builtin_amdgcn_s_setprio(0);

    #pragma unroll
    for (int mi = 0; mi < 4; ++mi)
        #pragma unroll
        for (int r = 0; r < 4; ++r) {
            int i = mi * 16 + q4 * 4 + r;
            if (i < 49) {
                int tok = rowbase + (i / 7) * 28 + (i % 7);
                u16* orow = ao + (size_t)tok * 512 + head * 32 + r15;
                orow[0]  = f2bf(o[mi][0][r]);
                orow[16] = f2bf(o[mi][1][r]);
            }
        }
}

// ---------------- launcher ----------------
extern "C" void kernel_launch(void* const* d_in, const int* in_sizes, int n_in,
                              void* d_out, int out_size, void* d_ws, size_t ws_size,
                              hipStream_t stream) {
    const float* x     = (const float*)d_in[0];
    const float* qg    = (const float*)d_in[1];
    const float* n1w   = (const float*)d_in[2];
    const float* n1b   = (const float*)d_in[3];
    const float* qkvw  = (const float*)d_in[4];
    const float* qkvb  = (const float*)d_in[5];
    const float* rbt   = (const float*)d_in[6];
    const float* projw = (const float*)d_in[7];
    const float* projb = (const float*)d_in[8];
    const float* n2w   = (const float*)d_in[9];
    const float* n2b   = (const float*)d_in[10];
    const float* fc1w  = (const float*)d_in[11];
    const float* fc1b  = (const float*)d_in[12];
    const float* fc2w  = (const float*)d_in[13];
    const float* fc2b  = (const float*)d_in[14];

    char* ws = (char*)d_ws;
    u16* wq = (u16*)(ws + 0);          // qkv_w bf16   [1024,512]
    u16* wp = (u16*)(ws + 1048576);    // proj_w bf16  [512,512]
    u16* w1 = (u16*)(ws + 1572864);    // fc1_w bf16   [2048,512]
    u16* w2 = (u16*)(ws + 3670016);    // fc2_w bf16   [512,2048]
    u16* h  = (u16*)(ws + 7864320);    // h / h2 bf16  [25088,512]
    u16* kv = (u16*)(ws + 33554432);   // kv bf16 [25088,1024] / m1 bf16 [25088,2048]
    u16* ao = (u16*)(ws + 136314880);  // attn out bf16 [25088,512]
    float* xres = (float*)d_out;       // fp32 residual lives in d_out

    // fused LN1 + weight conversion (cvt blocks appended after the 25088 LN rows)
    ln_cvt_kernel<<<25088 + 1024, 64, 0, stream>>>(x, n1w, n1b, h,
                                                   qkvw, wq, projw, wp, fc1w, w1, fc2w, w2);
    gemm_kernel<EPI_BF16><<<dim3(8, 196),  256, 0, stream>>>(h,  wq, qkvb, nullptr, kv, 1024, 512);
    attn_kernel<<<8192, 64, 0, stream>>>(kv, qg, rbt, ao);
    gemm_kernel<EPI_RES ><<<dim3(4, 196),  256, 0, stream>>>(ao, wp, projb, x, xres, 512, 512);
    ln_kernel<<<25088, 64, 0, stream>>>(xres, n2w, n2b, h);
    gemm_kernel<EPI_GELU><<<dim3(16, 196), 256, 0, stream>>>(h,  w1, fc1b, nullptr, kv /*m1*/, 2048, 512);
    gemm_kernel<EPI_RES ><<<dim3(4, 196),  256, 0, stream>>>(kv, w2, fc2b, xres, (float*)d_out, 512, 2048);
}

// Round 8
// 318.922 us; speedup vs baseline: 1.0764x; 1.0764x over previous
//
#include <hip/hip_runtime.h>

typedef unsigned int u32;
typedef unsigned short u16;
typedef __attribute__((ext_vector_type(8))) short short8;
typedef __attribute__((ext_vector_type(4))) float f32x4;

static __device__ __forceinline__ u16 f2bf(float f) {
    u32 u = __builtin_bit_cast(u32, f);
    u32 r = (u + 0x7fffu + ((u >> 16) & 1u)) >> 16;   // round-to-nearest-even
    return (u16)r;
}
static __device__ __forceinline__ float bf2f(u16 b) {
    return __builtin_bit_cast(float, ((u32)b) << 16);
}

// fast erf-based exact-GELU (Abramowitz-Stegun 7.1.26, |eps|<=1.5e-7)
static __device__ __forceinline__ float fast_gelu(float v) {
    float z = fabsf(v) * 0.70710678118654752f;
    float t = __builtin_amdgcn_rcpf(1.f + 0.3275911f * z);
    float poly = t * (0.254829592f + t * (-0.284496736f + t * (1.421413741f
               + t * (-1.453152027f + t * 1.061405429f))));
    float e = __expf(-z * z);
    float erfz = 1.f - poly * e;
    float sgn = v < 0.f ? -erfz : erfz;
    return 0.5f * v * (1.f + sgn);
}

static __device__ __forceinline__ void cvt_seg(const float* __restrict__ s, u16* __restrict__ d,
                                               int n4, int base, int stride) {
    for (int i = base; i < n4; i += stride) {
        float4 v = ((const float4*)s)[i];
        ushort4 p;
        p.x = f2bf(v.x); p.y = f2bf(v.y); p.z = f2bf(v.z); p.w = f2bf(v.w);
        ((ushort4*)d)[i] = p;
    }
}

static __device__ __forceinline__ void ln_row(const float* __restrict__ x, const float* __restrict__ w,
                                              const float* __restrict__ b, u16* __restrict__ out,
                                              int row, int t) {
    const float4* xr = (const float4*)(x + (size_t)row * 512);
    float4 v0 = xr[t * 2], v1 = xr[t * 2 + 1];
    float s  = v0.x + v0.y + v0.z + v0.w + v1.x + v1.y + v1.z + v1.w;
    float s2 = v0.x*v0.x + v0.y*v0.y + v0.z*v0.z + v0.w*v0.w
             + v1.x*v1.x + v1.y*v1.y + v1.z*v1.z + v1.w*v1.w;
    #pragma unroll
    for (int off = 32; off >= 1; off >>= 1) {
        s  += __shfl_xor(s, off);
        s2 += __shfl_xor(s2, off);
    }
    float mu   = s * (1.f / 512.f);
    float var  = s2 * (1.f / 512.f) - mu * mu;
    float rstd = rsqrtf(var + 1e-5f);
    int c = t * 8;
    float xv[8] = {v0.x, v0.y, v0.z, v0.w, v1.x, v1.y, v1.z, v1.w};
    short8 pk;
    #pragma unroll
    for (int j = 0; j < 8; ++j) {
        float y = (xv[j] - mu) * rstd * w[c + j] + b[c + j];
        pk[j] = (short)f2bf(y);
    }
    *(short8*)(out + (size_t)row * 512 + c) = pk;
}

// ---------------- LayerNorm (C=512), one row per 64-thread block ----------------
__global__ __launch_bounds__(64)
void ln_kernel(const float* __restrict__ x, const float* __restrict__ w,
               const float* __restrict__ b, u16* __restrict__ out) {
    ln_row(x, w, b, out, blockIdx.x, threadIdx.x);
}

// ---------------- fused: LN1 (blocks < 25088) + weight cvt (blocks >= 25088) ----------------
__global__ __launch_bounds__(64)
void ln_cvt_kernel(const float* __restrict__ x, const float* __restrict__ w,
                   const float* __restrict__ b, u16* __restrict__ out,
                   const float* s0, u16* d0, const float* s1, u16* d1,
                   const float* s2, u16* d2, const float* s3, u16* d3) {
    if (blockIdx.x < 25088) {
        ln_row(x, w, b, out, blockIdx.x, threadIdx.x);
    } else {
        int base = (blockIdx.x - 25088) * 64 + threadIdx.x;
        const int stride = 1024 * 64;
        cvt_seg(s0, d0, 131072, base, stride);   // qkv_w  524288/4
        cvt_seg(s1, d1, 65536,  base, stride);   // proj_w 262144/4
        cvt_seg(s2, d2, 262144, base, stride);   // fc1_w 1048576/4
        cvt_seg(s3, d3, 262144, base, stride);   // fc2_w 1048576/4
    }
}

// ---------------- bf16 MFMA GEMM: out[M,N] = A[M,K] @ W[N,K]^T + bias (+epilogue) ----------------
// 128x128 tile, BK=64, 4 waves (2x2 of 64x64), mfma_f32_16x16x32_bf16.
// Row-major LDS tiles with 16B-slot XOR swizzle; inverse-swizzled global source
// for global_load_lds (both-sides-or-neither rule). 32x32 MFMA was tried and
// regressed: 4-way bank conflict is structural at this layout (rows r,r+8,r+16,
// r+24 share an XOR slot) -- keep 16x16.
#define EPI_BF16 0
#define EPI_RES  1
#define EPI_GELU 2

template<int EPI>
__global__ __launch_bounds__(256, 2)
void gemm_kernel(const u16* __restrict__ A, const u16* __restrict__ W,
                 const float* __restrict__ bias, const float* resid,
                 void* out, int N, int K) {
    __shared__ __attribute__((aligned(16))) char ldsA[128 * 64 * 2];
    __shared__ __attribute__((aligned(16))) char ldsB[128 * 64 * 2];
    const int tid  = threadIdx.x;
    const int lane = tid & 63;
    const int wid  = tid >> 6;

    // XCD-chunked block swizzle: each XCD gets a contiguous tile range (x-fast)
    u32 nbx = gridDim.x;
    u32 bid = blockIdx.y * nbx + blockIdx.x;
    u32 nb  = nbx * gridDim.y;
    u32 tile = bid;
    if ((nb & 7u) == 0u) tile = (bid & 7u) * (nb >> 3) + (bid >> 3);
    const int tileM = (int)(tile / nbx) * 128;
    const int tileN = (int)(tile % nbx) * 128;

    const int waveM = (wid >> 1) * 64;
    const int waveN = (wid & 1) * 64;
    const int r8 = lane >> 3, c8 = lane & 7;
    const int swz = (c8 ^ r8) * 8;          // inverse-swizzled source column (elements)

    f32x4 acc[4][4] = {};

    const char* Ab = (const char*)A;
    const char* Wb = (const char*)W;

    for (int k0 = 0; k0 < K; k0 += 64) {
        #pragma unroll
        for (int i = 0; i < 4; ++i) {
            int chunk = wid * 4 + i;            // wave-uniform
            int row = chunk * 8 + r8;
            const char* ga = Ab + ((size_t)(tileM + row) * K + k0 + swz) * 2;
            const char* gb = Wb + ((size_t)(tileN + row) * K + k0 + swz) * 2;
            __builtin_amdgcn_global_load_lds((const __attribute__((address_space(1))) u32*)ga,
                (__attribute__((address_space(3))) u32*)(ldsA + chunk * 1024), 16, 0, 0);
            __builtin_amdgcn_global_load_lds((const __attribute__((address_space(1))) u32*)gb,
                (__attribute__((address_space(3))) u32*)(ldsB + chunk * 1024), 16, 0, 0);
        }
        __syncthreads();
        #pragma unroll
        for (int kk = 0; kk < 2; ++kk) {
            short8 aF[4], bF[4];
            int kByte = kk * 64 + ((lane >> 4) * 16);
            #pragma unroll
            for (int m = 0; m < 4; ++m) {
                int row = waveM + m * 16 + (lane & 15);
                aF[m] = *(const short8*)(ldsA + row * 128 + (kByte ^ ((row & 7) << 4)));
            }
            #pragma unroll
            for (int n = 0; n < 4; ++n) {
                int row = waveN + n * 16 + (lane & 15);
                bF[n] = *(const short8*)(ldsB + row * 128 + (kByte ^ ((row & 7) << 4)));
            }
            #pragma unroll
            for (int m = 0; m < 4; ++m)
                #pragma unroll
                for (int n = 0; n < 4; ++n)
                    acc[m][n] = __builtin_amdgcn_mfma_f32_16x16x32_bf16(aF[m], bF[n], acc[m][n], 0, 0, 0);
        }
        __syncthreads();
    }

    // epilogue: C/D layout col = lane&15, row = (lane>>4)*4 + r
    #pragma unroll
    for (int m = 0; m < 4; ++m) {
        #pragma unroll
        for (int n = 0; n < 4; ++n) {
            int col = tileN + waveN + n * 16 + (lane & 15);
            float bv = bias[col];
            #pragma unroll
            for (int r = 0; r < 4; ++r) {
                int row = tileM + waveM + m * 16 + (lane >> 4) * 4 + r;
                float v = acc[m][n][r] + bv;
                if (EPI == EPI_GELU) v = fast_gelu(v);
                if (EPI == EPI_RES) {
                    v += resid[(size_t)row * N + col];
                    ((float*)out)[(size_t)row * N + col] = v;
                } else {
                    ((u16*)out)[(size_t)row * N + col] = f2bf(v);
                }
            }
        }
    }
}

// ---------------- MFMA attention: 1 wave per (window, head), 49 padded to 64 ----------------
__global__ __launch_bounds__(64)
void attn_kernel(const u16* __restrict__ kv, const float* __restrict__ qg,
                 const float* __restrict__ bt, u16* __restrict__ ao) {
    __shared__ u16 Vt[32][72];   // V^T, 144B pitch -> bank stride 4, 2-way (free)
    __shared__ u16 P[64][72];    // P[i][j] bf16, same pitch
    const int lane = threadIdx.x;
    const int q4 = lane >> 4, r15 = lane & 15;
    const int head = blockIdx.x & 15;
    const int w = blockIdx.x >> 4;
    const int b = w >> 4, win = w & 15, wy = win >> 2, wx = win & 3;
    const int rowbase = (b * 28 + wy * 7) * 28 + wx * 7;

    short8 kF[4];
    #pragma unroll
    for (int mj = 0; mj < 4; ++mj) {
        int j = mj * 16 + r15; int jc = j < 49 ? j : 48;
        int tok = rowbase + (jc / 7) * 28 + (jc % 7);
        kF[mj] = *(const short8*)(kv + (size_t)tok * 1024 + head * 32 + q4 * 8);
    }
    short8 qF[4];
    const float* qbase = qg + ((size_t)(b * 16 + head)) * 49 * 32;
    #pragma unroll
    for (int ni = 0; ni < 4; ++ni) {
        int i = ni * 16 + r15; int ic = i < 49 ? i : 48;
        const float4* qr = (const float4*)(qbase + ic * 32 + q4 * 8);
        float4 a = qr[0], c = qr[1];
        short8 f;
        f[0] = (short)f2bf(a.x * 0.17677669529663687f);
        f[1] = (short)f2bf(a.y * 0.17677669529663687f);
        f[2] = (short)f2bf(a.z * 0.17677669529663687f);
        f[3] = (short)f2bf(a.w * 0.17677669529663687f);
        f[4] = (short)f2bf(c.x * 0.17677669529663687f);
        f[5] = (short)f2bf(c.y * 0.17677669529663687f);
        f[6] = (short)f2bf(c.z * 0.17677669529663687f);
        f[7] = (short)f2bf(c.w * 0.17677669529663687f);
        qF[ni] = f;
    }
    {
        int j = lane;
        short8 v0 = {}, v1 = {}, v2 = {}, v3 = {};
        if (j < 49) {
            int tok = rowbase + (j / 7) * 28 + (j % 7);
            const short8* vr = (const short8*)(kv + (size_t)tok * 1024 + 512 + head * 32);
            v0 = vr[0]; v1 = vr[1]; v2 = vr[2]; v3 = vr[3];
        }
        #pragma unroll
        for (int e = 0; e < 8; ++e) {
            Vt[e][j]      = (u16)v0[e];
            Vt[8 + e][j]  = (u16)v1[e];
            Vt[16 + e][j] = (u16)v2[e];
            Vt[24 + e][j] = (u16)v3[e];
        }
    }

    f32x4 s[4][4];
    __builtin_amdgcn_s_setprio(1);
    #pragma unroll
    for (int mj = 0; mj < 4; ++mj)
        #pragma unroll
        for (int ni = 0; ni < 4; ++ni)
            s[mj][ni] = __builtin_amdgcn_mfma_f32_16x16x32_bf16(kF[mj], qF[ni], (f32x4){0.f,0.f,0.f,0.f}, 0, 0, 0);
    __builtin_amdgcn_s_setprio(0);

    int tj16[4][4]; bool jok[4][4];
    #pragma unroll
    for (int mj = 0; mj < 4; ++mj)
        #pragma unroll
        for (int r = 0; r < 4; ++r) {
            int j = mj * 16 + q4 * 4 + r;
            int jc = j < 49 ? j : 48;
            tj16[mj][r] = ((jc / 7) * 13 + (jc % 7)) * 16;
            jok[mj][r] = (j < 49);
        }

    #pragma unroll
    for (int ni = 0; ni < 4; ++ni) {
        int i = ni * 16 + r15; int ic = i < 49 ? i : 48;
        const float* btbase = bt + (((ic / 7) * 13 + (ic % 7)) + 84) * 16 + head;
        float mx = -1e30f;
        #pragma unroll
        for (int mj = 0; mj < 4; ++mj)
            #pragma unroll
            for (int r = 0; r < 4; ++r) {
                float v = s[mj][ni][r] + btbase[-tj16[mj][r]];
                v = jok[mj][r] ? v : -1e30f;
                s[mj][ni][r] = v;
                mx = fmaxf(mx, v);
            }
        mx = fmaxf(mx, __shfl_xor(mx, 16));
        mx = fmaxf(mx, __shfl_xor(mx, 32));
        float l = 0.f;
        #pragma unroll
        for (int mj = 0; mj < 4; ++mj)
            #pragma unroll
            for (int r = 0; r < 4; ++r) {
                float p = __expf(s[mj][ni][r] - mx);
                s[mj][ni][r] = p;
                l += p;
            }
        l += __shfl_xor(l, 16);
        l += __shfl_xor(l, 32);
        float inv = 1.f / l;
        #pragma unroll
        for (int mj = 0; mj < 4; ++mj) {
            ushort4 pk;
            pk.x = f2bf(s[mj][ni][0] * inv);
            pk.y = f2bf(s[mj][ni][1] * inv);
            pk.z = f2bf(s[mj][ni][2] * inv);
            pk.w = f2bf(s[mj][ni][3] * inv);
            *(ushort4*)&P[i][mj * 16 + q4 * 4] = pk;
        }
    }
    __syncthreads();

    f32x4 o[4][2] = {};
    __builtin_amdgcn_s_setprio(1);
    #pragma unroll
    for (int ks = 0; ks < 2; ++ks) {
        short8 vB0 = *(const short8*)&Vt[r15][ks * 16 + q4 * 8];
        short8 vB1 = *(const short8*)&Vt[16 + r15][ks * 16 + q4 * 8];
        #pragma unroll
        for (int mi = 0; mi < 4; ++mi) {
            short8 pA = *(const short8*)&P[mi * 16 + r15][ks * 16 + q4 * 8];
            o[mi][0] = __builtin_amdgcn_mfma_f32_16x16x32_bf16(pA, vB0, o[mi][0], 0, 0, 0);
            o[mi][1] = __builtin_amdgcn_mfma_f32_16x16x32_bf16(pA, vB1, o[mi][1], 0, 0, 0);
        }
    }
    __builtin_amdgcn_s_setprio(0);

    #pragma unroll
    for (int mi = 0; mi < 4; ++mi)
        #pragma unroll
        for (int r = 0; r < 4; ++r) {
            int i = mi * 16 + q4 * 4 + r;
            if (i < 49) {
                int tok = rowbase + (i / 7) * 28 + (i % 7);
                u16* orow = ao + (size_t)tok * 512 + head * 32 + r15;
                orow[0]  = f2bf(o[mi][0][r]);
                orow[16] = f2bf(o[mi][1][r]);
            }
        }
}

// ---------------- launcher ----------------
extern "C" void kernel_launch(void* const* d_in, const int* in_sizes, int n_in,
                              void* d_out, int out_size, void* d_ws, size_t ws_size,
                              hipStream_t stream) {
    const float* x     = (const float*)d_in[0];
    const float* qg    = (const float*)d_in[1];
    const float* n1w   = (const float*)d_in[2];
    const float* n1b   = (const float*)d_in[3];
    const float* qkvw  = (const float*)d_in[4];
    const float* qkvb  = (const float*)d_in[5];
    const float* rbt   = (const float*)d_in[6];
    const float* projw = (const float*)d_in[7];
    const float* projb = (const float*)d_in[8];
    const float* n2w   = (const float*)d_in[9];
    const float* n2b   = (const float*)d_in[10];
    const float* fc1w  = (const float*)d_in[11];
    const float* fc1b  = (const float*)d_in[12];
    const float* fc2w  = (const float*)d_in[13];
    const float* fc2b  = (const float*)d_in[14];

    char* ws = (char*)d_ws;
    u16* wq = (u16*)(ws + 0);          // qkv_w bf16   [1024,512]
    u16* wp = (u16*)(ws + 1048576);    // proj_w bf16  [512,512]
    u16* w1 = (u16*)(ws + 1572864);    // fc1_w bf16   [2048,512]
    u16* w2 = (u16*)(ws + 3670016);    // fc2_w bf16   [512,2048]
    u16* h  = (u16*)(ws + 7864320);    // h / h2 bf16  [25088,512]
    u16* kv = (u16*)(ws + 33554432);   // kv bf16 [25088,1024] / m1 bf16 [25088,2048]
    u16* ao = (u16*)(ws + 136314880);  // attn out bf16 [25088,512]
    float* xres = (float*)d_out;       // fp32 residual lives in d_out

    // fused LN1 + weight conversion (cvt blocks appended after the 25088 LN rows)
    ln_cvt_kernel<<<25088 + 1024, 64, 0, stream>>>(x, n1w, n1b, h,
                                                   qkvw, wq, projw, wp, fc1w, w1, fc2w, w2);
    gemm_kernel<EPI_BF16><<<dim3(8, 196),  256, 0, stream>>>(h,  wq, qkvb, nullptr, kv, 1024, 512);
    attn_kernel<<<8192, 64, 0, stream>>>(kv, qg, rbt, ao);
    gemm_kernel<EPI_RES ><<<dim3(4, 196),  256, 0, stream>>>(ao, wp, projb, x, xres, 512, 512);
    ln_kernel<<<25088, 64, 0, stream>>>(xres, n2w, n2b, h);
    gemm_kernel<EPI_GELU><<<dim3(16, 196), 256, 0, stream>>>(h,  w1, fc1b, nullptr, kv /*m1*/, 2048, 512);
    gemm_kernel<EPI_RES ><<<dim3(4, 196),  256, 0, stream>>>(kv, w2, fc2b, xres, (float*)d_out, 512, 2048);
}